// Round 1
// baseline (255.699 us; speedup 1.0000x reference)
//
#include <hip/hip_runtime.h>

#define B_   32
#define C_   16
#define H_   128
#define W_   128
#define HW_  (H_ * W_)
#define NF_  4
#define HID_ 128
#define FIN_ (C_ * NF_)   // 64
#define NPIX (B_ * HW_)   // 524288

// Kernel A: perceive (depthwise 3x3 circular conv, 4 filters) + MLP 64->128->16
// + masked update. Writes x_new to out, new alpha plane + pre_life to ws.
__global__ __launch_bounds__(256) void ca_step(
    const float* __restrict__ x,
    const float* __restrict__ rmask,
    const float* __restrict__ filt,
    const float* __restrict__ W1,
    const float* __restrict__ b1,
    const float* __restrict__ W2,
    const float* __restrict__ b2,
    float* __restrict__ out,
    float* __restrict__ alpha_new,
    float* __restrict__ pre_life)
{
    int tid = blockIdx.x * blockDim.x + threadIdx.x;
    if (tid >= NPIX) return;
    int b   = tid >> 14;          // / HW_
    int pix = tid & (HW_ - 1);
    int r   = pix >> 7;           // / W_
    int c   = pix & (W_ - 1);

    int rm = (r - 1) & (H_ - 1), rp = (r + 1) & (H_ - 1);
    int cm = (c - 1) & (W_ - 1), cp = (c + 1) & (W_ - 1);
    int off[9] = { rm * W_ + cm, rm * W_ + c, rm * W_ + cp,
                   r  * W_ + cm, r  * W_ + c, r  * W_ + cp,
                   rp * W_ + cm, rp * W_ + c, rp * W_ + cp };

    const float* xb = x + (size_t)b * C_ * HW_;

    float y[FIN_];
    float premax = -1e30f, presum = 0.f;

    #pragma unroll
    for (int ch = 0; ch < C_; ++ch) {
        const float* xc = xb + ch * HW_;
        float n[9];
        #pragma unroll
        for (int t = 0; t < 9; ++t) n[t] = xc[off[t]];
        #pragma unroll
        for (int f = 0; f < NF_; ++f) {
            float a = 0.f;
            #pragma unroll
            for (int t = 0; t < 9; ++t) a = fmaf(filt[f * 9 + t], n[t], a);
            y[ch * NF_ + f] = a;
        }
        if (ch == 3) {
            float mx = n[0], sm = 0.f;
            #pragma unroll
            for (int t = 0; t < 9; ++t) { mx = fmaxf(mx, n[t]); sm += n[t]; }
            premax = mx; presum = sm;
        }
    }
    float pre = (premax > 0.1f && (presum / 9.0f) < 0.2f) ? 1.f : 0.f;

    // MLP: h = leaky(W1 @ y + b1); dx = W2 @ h + b2
    float acc[C_];
    #pragma unroll
    for (int j = 0; j < C_; ++j) acc[j] = b2[j];
    for (int o = 0; o < HID_; ++o) {
        float h = b1[o];
        #pragma unroll
        for (int k = 0; k < FIN_; ++k) h = fmaf(W1[o * FIN_ + k], y[k], h);
        h = (h >= 0.f) ? h : 0.01f * h;
        #pragma unroll
        for (int j = 0; j < C_; ++j) acc[j] = fmaf(W2[j * HID_ + o], h, acc[j]);
    }

    float um = (rmask[b * HW_ + pix] <= 0.5f) ? 1.f : 0.f;

    float* ob = out + (size_t)b * C_ * HW_ + pix;
    float an = 0.f;
    #pragma unroll
    for (int ch = 0; ch < C_; ++ch) {
        float xv = xb[ch * HW_ + off[4]];
        float xn = xv + acc[ch] * um;
        ob[ch * HW_] = xn;
        if (ch == 3) an = xn;
    }
    alpha_new[tid] = an;
    pre_life[tid]  = pre;
}

// Kernel B: post_life from new alpha plane; zero channels where !(pre & post).
__global__ __launch_bounds__(256) void ca_mask(
    const float* __restrict__ alpha_new,
    const float* __restrict__ pre_life,
    float* __restrict__ out)
{
    int tid = blockIdx.x * blockDim.x + threadIdx.x;
    if (tid >= NPIX) return;
    int b   = tid >> 14;
    int pix = tid & (HW_ - 1);
    int r   = pix >> 7;
    int c   = pix & (W_ - 1);

    int rm = (r - 1) & (H_ - 1), rp = (r + 1) & (H_ - 1);
    int cm = (c - 1) & (W_ - 1), cp = (c + 1) & (W_ - 1);
    int off[9] = { rm * W_ + cm, rm * W_ + c, rm * W_ + cp,
                   r  * W_ + cm, r  * W_ + c, r  * W_ + cp,
                   rp * W_ + cm, rp * W_ + c, rp * W_ + cp };

    const float* ab = alpha_new + (size_t)b * HW_;
    float mx = -1e30f, sm = 0.f;
    #pragma unroll
    for (int t = 0; t < 9; ++t) {
        float v = ab[off[t]];
        mx = fmaxf(mx, v);
        sm += v;
    }
    bool post = (mx > 0.1f) && ((sm / 9.0f) < 0.2f);
    bool life = post && (pre_life[tid] > 0.5f);
    if (!life) {
        float* ob = out + (size_t)b * C_ * HW_ + pix;
        #pragma unroll
        for (int ch = 0; ch < C_; ++ch) ob[ch * HW_] = 0.f;
    }
}

extern "C" void kernel_launch(void* const* d_in, const int* in_sizes, int n_in,
                              void* d_out, int out_size, void* d_ws, size_t ws_size,
                              hipStream_t stream)
{
    const float* x     = (const float*)d_in[0];
    const float* rmask = (const float*)d_in[1];
    const float* filt  = (const float*)d_in[2];
    const float* W1    = (const float*)d_in[3];
    const float* b1    = (const float*)d_in[4];
    const float* W2    = (const float*)d_in[5];
    const float* b2    = (const float*)d_in[6];
    float* out = (float*)d_out;

    float* alpha_new = (float*)d_ws;           // NPIX floats
    float* pre_life  = alpha_new + NPIX;       // NPIX floats

    dim3 blk(256);
    dim3 grd((NPIX + 255) / 256);
    ca_step<<<grd, blk, 0, stream>>>(x, rmask, filt, W1, b1, W2, b2,
                                     out, alpha_new, pre_life);
    ca_mask<<<grd, blk, 0, stream>>>(alpha_new, pre_life, out);
}